// Round 2
// baseline (108.660 us; speedup 1.0000x reference)
//
#include <hip/hip_runtime.h>

#define NN 1024   // pair count
#define HH 128    // hidden per side
#define KK 256    // 2*HIDDEN, premlp width

typedef float f32x2 __attribute__((ext_vector_type(2)));

// Prologue:
//   HA [m][k] (m-major, [1024][256]) = dot(pred_a[m,:], W1[k,0:128]) + b1[k]
//   HBT[k][j] (k-major, [256][1024]) = dot(pred_b[j,:], W1[k,128:256])
// Grid: 256 blocks x 256 threads. Blocks 0..127 -> HA (8 m each), 128..255 -> HBT (8 j each).
__global__ __launch_bounds__(256) void prologue_kernel(
    const float* __restrict__ pred_a, const float* __restrict__ pred_b,
    const float* __restrict__ W1, const float* __restrict__ b1,
    float* __restrict__ HA, float* __restrict__ HBT)
{
    const int k = threadIdx.x;                 // output channel 0..255
    const int blk = blockIdx.x;
    const bool isB = blk >= 128;
    const int mbase = (isB ? blk - 128 : blk) * 8;
    const float* __restrict__ src = isB ? pred_b : pred_a;
    const float* __restrict__ wrow = W1 + k * KK + (isB ? HH : 0);

    float acc[8];
    const float init = isB ? 0.0f : b1[k];
    #pragma unroll
    for (int mm = 0; mm < 8; ++mm) acc[mm] = init;

    for (int i0 = 0; i0 < HH; i0 += 4) {
        const float4 w = *reinterpret_cast<const float4*>(wrow + i0);  // per-lane 16B
        #pragma unroll
        for (int mm = 0; mm < 8; ++mm) {
            // uniform address -> s_load_dwordx4
            const float4 p = *reinterpret_cast<const float4*>(src + (mbase + mm) * HH + i0);
            float a = acc[mm];
            a = fmaf(p.x, w.x, a);
            a = fmaf(p.y, w.y, a);
            a = fmaf(p.z, w.z, a);
            a = fmaf(p.w, w.w, a);
            acc[mm] = a;
        }
    }

    if (!isB) {
        #pragma unroll
        for (int mm = 0; mm < 8; ++mm)
            HA[(mbase + mm) * KK + k] = acc[mm];          // coalesced over lanes (k)
    } else {
        #pragma unroll
        for (int c = 0; c < 2; ++c) {                      // per-lane contiguous 32B
            float4 v = make_float4(acc[4*c+0], acc[4*c+1], acc[4*c+2], acc[4*c+3]);
            *reinterpret_cast<float4*>(HBT + k * NN + mbase + 4*c) = v;
        }
    }
}

// Main fused pair kernel:
//   out[m][j] = sum_k relu(HA[m][k] + HBT[k][j]) * W2[k] + b2
// Block = 256 thr (4 waves). Tile: 32 m x 64 j. Each wave: 8 m, lane = j.
// Packed over k-pairs: ha2/w22 as SGPR pairs feed VOP3P directly.
__global__ __launch_bounds__(256, 2) void pair_kernel(
    const float* __restrict__ HA, const float* __restrict__ HBT,
    const float* __restrict__ W2, const float* __restrict__ b2,
    float* __restrict__ out)
{
    __shared__ float lds[KK * 64];                 // [k][j], 64 KB, row = 64 floats
    const int t = threadIdx.x;
    const int lane = t & 63;
    const int wave = t >> 6;
    const int jbase = (blockIdx.x & 15) * 64;      // 16 j-tiles
    const int mbase = (blockIdx.x >> 4) * 32;      // 32 m-tiles

    // Stage: one wave reads 64 consecutive floats of an HBT row (256B coalesced),
    // writes one LDS row (lane-consecutive -> 2-way bank aliasing = free).
    #pragma unroll
    for (int c = 0; c < 64; ++c) {
        const int k = wave + c * 4;
        lds[k * 64 + lane] = HBT[k * NN + jbase + lane];
    }
    __syncthreads();

    // Wave-uniform m base in SGPR so HA reads become s_load_dwordx2.
    const int m_w = __builtin_amdgcn_readfirstlane(mbase + wave * 8);
    const float* __restrict__ ha0 = HA + m_w * KK;

    f32x2 acc2[8];
    #pragma unroll
    for (int mm = 0; mm < 8; ++mm) { acc2[mm].x = 0.0f; acc2[mm].y = 0.0f; }

    #pragma unroll 4
    for (int k0 = 0; k0 < KK; k0 += 2) {
        f32x2 hb2;
        hb2.x = lds[k0 * 64 + lane];              // ds_read_b32 (2-way, free)
        hb2.y = lds[(k0 + 1) * 64 + lane];        // may merge -> ds_read2_b32
        const f32x2 w22 = *reinterpret_cast<const f32x2*>(W2 + k0);   // s_load_dwordx2
        #pragma unroll
        for (int mm = 0; mm < 8; ++mm) {
            const f32x2 ha2 = *reinterpret_cast<const f32x2*>(ha0 + mm * KK + k0); // s_load_dwordx2
            f32x2 s2;
            asm("v_pk_add_f32 %0, %1, %2" : "=v"(s2) : "s"(ha2), "v"(hb2));
            s2.x = fmaxf(s2.x, 0.0f);             // v_max_f32
            s2.y = fmaxf(s2.y, 0.0f);             // v_max_f32
            asm("v_pk_fma_f32 %0, %1, %2, %0" : "+v"(acc2[mm]) : "v"(s2), "s"(w22));
        }
    }

    const float b2v = b2[0];
    #pragma unroll
    for (int mm = 0; mm < 8; ++mm)
        out[(m_w + mm) * NN + jbase + lane] = acc2[mm].x + acc2[mm].y + b2v;  // coalesced
}

extern "C" void kernel_launch(void* const* d_in, const int* in_sizes, int n_in,
                              void* d_out, int out_size, void* d_ws, size_t ws_size,
                              hipStream_t stream) {
    const float* pred_a = (const float*)d_in[0];
    const float* pred_b = (const float*)d_in[1];
    const float* W1     = (const float*)d_in[2];
    const float* b1     = (const float*)d_in[3];
    const float* W2     = (const float*)d_in[4];
    const float* b2     = (const float*)d_in[5];
    float* out = (float*)d_out;

    float* HA  = (float*)d_ws;           // 1024*256 floats = 1 MB
    float* HBT = HA + NN * KK;           // 256*1024 floats = 1 MB

    prologue_kernel<<<256, 256, 0, stream>>>(pred_a, pred_b, W1, b1, HA, HBT);
    pair_kernel<<<512, 256, 0, stream>>>(HA, HBT, W2, b2, out);
}

// Round 4
// 103.773 us; speedup vs baseline: 1.0471x; 1.0471x over previous
//
#include <hip/hip_runtime.h>

#define NN 1024   // pair count
#define HH 128    // hidden per side
#define KK 256    // 2*HIDDEN, premlp width

typedef float f32x2 __attribute__((ext_vector_type(2)));

// Prologue (correctness-proven in round 2):
//   HA [m][k] ([1024][256]) = dot(pred_a[m,:], W1[k,0:128]) + b1[k]
//   HBT[k][j] ([256][1024]) = dot(pred_b[j,:], W1[k,128:256])
__global__ __launch_bounds__(256) void prologue_kernel(
    const float* __restrict__ pred_a, const float* __restrict__ pred_b,
    const float* __restrict__ W1, const float* __restrict__ b1,
    float* __restrict__ HA, float* __restrict__ HBT)
{
    const int k = threadIdx.x;                 // output channel 0..255
    const int blk = blockIdx.x;
    const bool isB = blk >= 128;
    const int mbase = (isB ? blk - 128 : blk) * 8;
    const float* __restrict__ src = isB ? pred_b : pred_a;
    const float* __restrict__ wrow = W1 + k * KK + (isB ? HH : 0);

    float acc[8];
    const float init = isB ? 0.0f : b1[k];
    #pragma unroll
    for (int mm = 0; mm < 8; ++mm) acc[mm] = init;

    for (int i0 = 0; i0 < HH; i0 += 4) {
        const float4 w = *reinterpret_cast<const float4*>(wrow + i0);  // per-lane 16B
        #pragma unroll
        for (int mm = 0; mm < 8; ++mm) {
            const float4 p = *reinterpret_cast<const float4*>(src + (mbase + mm) * HH + i0);
            float a = acc[mm];
            a = fmaf(p.x, w.x, a);
            a = fmaf(p.y, w.y, a);
            a = fmaf(p.z, w.z, a);
            a = fmaf(p.w, w.w, a);
            acc[mm] = a;
        }
    }

    if (!isB) {
        #pragma unroll
        for (int mm = 0; mm < 8; ++mm)
            HA[(mbase + mm) * KK + k] = acc[mm];          // coalesced over lanes (k)
    } else {
        #pragma unroll
        for (int c = 0; c < 2; ++c) {
            float4 v = make_float4(acc[4*c+0], acc[4*c+1], acc[4*c+2], acc[4*c+3]);
            *reinterpret_cast<float4*>(HBT + k * NN + mbase + 4*c) = v;
        }
    }
}

// Main fused pair kernel: out[m][j] = sum_k relu(HA[m][k] + HBT[k][j]) * W2[k] + b2
// 1024 blocks x 256 thr. Tile 16m x 64j, k in two 128-phases.
// LDS: lha[16][128] (8KB) + lhb[128][64] (32KB) + lw2[128] (0.5KB) -> 3 blocks/CU.
// Hot loop is DS-only (no SMEM -> no coarse lgkmcnt serialization):
//   ha/w2 = wave-uniform ds_read_b128 broadcasts; hb = lane-indexed ds_read_b32 (2-way, free).
__global__ __launch_bounds__(256, 3) void pair_kernel(
    const float* __restrict__ HA, const float* __restrict__ HBT,
    const float* __restrict__ W2, const float* __restrict__ b2,
    float* __restrict__ out)
{
    __shared__ __align__(16) float lds[2048 + 8192 + 128];
    float* lha = lds;              // [m(16)][k(128)]
    float* lhb = lds + 2048;       // [k(128)][j(64)]
    float* lw2 = lds + 2048 + 8192;

    const int t = threadIdx.x;
    const int lane = t & 63;
    const int wave = t >> 6;
    const int jbase = (blockIdx.x & 15) * 64;       // 16 j-tiles
    const int mbase = (blockIdx.x >> 4) * 16;       // 64 m-tiles
    const int wm = wave * 4;                        // wave's m offset in tile

    f32x2 acc[4];
    #pragma unroll
    for (int mm = 0; mm < 4; ++mm) { acc[mm].x = 0.0f; acc[mm].y = 0.0f; }

    for (int kb = 0; kb < KK; kb += 128) {
        if (kb) __syncthreads();                    // WAR: done reading previous tile

        // ---- stage (all per-lane vector loads; coalesced) ----
        #pragma unroll
        for (int c = 0; c < 2; ++c) {               // HA tile: 2048 floats
            const int idx = c * 256 + t;
            const int row = idx >> 5, col = (idx & 31) << 2;
            *reinterpret_cast<float4*>(&lha[row * 128 + col]) =
                *reinterpret_cast<const float4*>(&HA[(mbase + row) * KK + kb + col]);
        }
        #pragma unroll
        for (int c = 0; c < 8; ++c) {               // HBT tile: 8192 floats
            const int idx = c * 256 + t;
            const int k = idx >> 4, col = (idx & 15) << 2;
            *reinterpret_cast<float4*>(&lhb[k * 64 + col]) =
                *reinterpret_cast<const float4*>(&HBT[(kb + k) * NN + jbase + col]);
        }
        if (t < 32)                                  // W2 chunk: 128 floats
            *reinterpret_cast<float4*>(&lw2[t * 4]) =
                *reinterpret_cast<const float4*>(&W2[kb + t * 4]);
        __syncthreads();

        // ---- compute: DS + VALU only ----
        #pragma unroll 4
        for (int k0 = 0; k0 < 128; k0 += 4) {
            f32x2 hb01, hb23;
            hb01.x = lhb[(k0 + 0) * 64 + lane];      // ds_read_b32, imm offsets
            hb01.y = lhb[(k0 + 1) * 64 + lane];
            hb23.x = lhb[(k0 + 2) * 64 + lane];
            hb23.y = lhb[(k0 + 3) * 64 + lane];
            const float4 w4 = *reinterpret_cast<const float4*>(&lw2[k0]);  // broadcast b128
            f32x2 w01; w01.x = w4.x; w01.y = w4.y;
            f32x2 w23; w23.x = w4.z; w23.y = w4.w;
            #pragma unroll
            for (int mm = 0; mm < 4; ++mm) {
                const float4 a4 = *reinterpret_cast<const float4*>(&lha[(wm + mm) * 128 + k0]); // broadcast b128
                f32x2 a01; a01.x = a4.x; a01.y = a4.y;
                f32x2 a23; a23.x = a4.z; a23.y = a4.w;
                f32x2 s;
                asm("v_pk_add_f32 %0, %1, %2" : "=v"(s) : "v"(a01), "v"(hb01));
                s.x = fmaxf(s.x, 0.0f);
                s.y = fmaxf(s.y, 0.0f);
                asm("v_pk_fma_f32 %0, %1, %2, %0" : "+v"(acc[mm]) : "v"(s), "v"(w01));
                f32x2 r;
                asm("v_pk_add_f32 %0, %1, %2" : "=v"(r) : "v"(a23), "v"(hb23));
                r.x = fmaxf(r.x, 0.0f);
                r.y = fmaxf(r.y, 0.0f);
                asm("v_pk_fma_f32 %0, %1, %2, %0" : "+v"(acc[mm]) : "v"(r), "v"(w23));
            }
        }
    }

    const float b2v = b2[0];
    #pragma unroll
    for (int mm = 0; mm < 4; ++mm)
        out[(mbase + wm + mm) * NN + jbase + lane] = acc[mm].x + acc[mm].y + b2v;  // coalesced
}

extern "C" void kernel_launch(void* const* d_in, const int* in_sizes, int n_in,
                              void* d_out, int out_size, void* d_ws, size_t ws_size,
                              hipStream_t stream) {
    const float* pred_a = (const float*)d_in[0];
    const float* pred_b = (const float*)d_in[1];
    const float* W1     = (const float*)d_in[2];
    const float* b1     = (const float*)d_in[3];
    const float* W2     = (const float*)d_in[4];
    const float* b2     = (const float*)d_in[5];
    float* out = (float*)d_out;

    float* HA  = (float*)d_ws;           // 1024*256 floats = 1 MB
    float* HBT = HA + NN * KK;           // 256*1024 floats = 1 MB

    prologue_kernel<<<256, 256, 0, stream>>>(pred_a, pred_b, W1, b1, HA, HBT);
    pair_kernel<<<1024, 256, 0, stream>>>(HA, HBT, W2, b2, out);
}

// Round 6
// 103.451 us; speedup vs baseline: 1.0504x; 1.0031x over previous
//
#include <hip/hip_runtime.h>

#define NN 1024   // pair count
#define HH 128    // hidden per side
#define KK 256    // 2*HIDDEN, premlp width

typedef float f32x2 __attribute__((ext_vector_type(2)));

// Prologue v2 — VMEM-only hot loop (NO scalar loads), 512 blocks = 2/CU.
//   HA [m][k] ([1024][256]) = dot(pred_a[m,:], W1[k,0:128]) + b1[k]
//   HBT[k][j] ([256][1024]) = dot(pred_b[j,:], W1[k,128:256])
// Even blocks -> HA (4 m-rows), odd blocks -> HBT (4 j-rows).
__global__ __launch_bounds__(256, 2) void prologue_kernel(
    const float* __restrict__ pred_a, const float* __restrict__ pred_b,
    const float* __restrict__ W1, const float* __restrict__ b1,
    float* __restrict__ HA, float* __restrict__ HBT)
{
    __shared__ __align__(16) float lin[4 * HH];    // 4 input rows, 2 KB
    const int t = threadIdx.x;
    const int k = t;                               // output channel 0..255
    const bool isB = blockIdx.x & 1;
    const int rowbase = (blockIdx.x >> 1) * 4;     // 256 groups of 4 rows
    const float* __restrict__ src = isB ? pred_b : pred_a;
    const float* __restrict__ wrow = W1 + k * KK + (isB ? HH : 0);

    if (t < 128) {                                 // stage 4 input rows, coalesced
        const int row = t >> 5, col = (t & 31) << 2;
        *reinterpret_cast<float4*>(&lin[row * HH + col]) =
            *reinterpret_cast<const float4*>(&src[(rowbase + row) * HH + col]);
    }
    const float bias = isB ? 0.0f : b1[k];         // per-lane coalesced dword
    __syncthreads();

    float acc0 = 0.f, acc1 = 0.f, acc2 = 0.f, acc3 = 0.f;
    #pragma unroll 8
    for (int i0 = 0; i0 < HH; i0 += 4) {
        // per-lane global float4 (independent addrs -> deep MLP, hides cold HBM)
        const float4 w = *reinterpret_cast<const float4*>(wrow + i0);
        // LDS broadcasts (all lanes same addr -> conflict-free)
        const float4 p0 = *reinterpret_cast<const float4*>(&lin[0 * HH + i0]);
        const float4 p1 = *reinterpret_cast<const float4*>(&lin[1 * HH + i0]);
        const float4 p2 = *reinterpret_cast<const float4*>(&lin[2 * HH + i0]);
        const float4 p3 = *reinterpret_cast<const float4*>(&lin[3 * HH + i0]);
        acc0 = fmaf(w.x,p0.x, fmaf(w.y,p0.y, fmaf(w.z,p0.z, fmaf(w.w,p0.w, acc0))));
        acc1 = fmaf(w.x,p1.x, fmaf(w.y,p1.y, fmaf(w.z,p1.z, fmaf(w.w,p1.w, acc1))));
        acc2 = fmaf(w.x,p2.x, fmaf(w.y,p2.y, fmaf(w.z,p2.z, fmaf(w.w,p2.w, acc2))));
        acc3 = fmaf(w.x,p3.x, fmaf(w.y,p3.y, fmaf(w.z,p3.z, fmaf(w.w,p3.w, acc3))));
    }

    if (!isB) {
        HA[(rowbase + 0) * KK + k] = acc0 + bias;  // coalesced over k
        HA[(rowbase + 1) * KK + k] = acc1 + bias;
        HA[(rowbase + 2) * KK + k] = acc2 + bias;
        HA[(rowbase + 3) * KK + k] = acc3 + bias;
    } else {
        float4 v = make_float4(acc0, acc1, acc2, acc3);
        *reinterpret_cast<float4*>(HBT + k * NN + rowbase) = v;  // 16B/lane
    }
}

// Main fused pair kernel (UNCHANGED from round 4 — single-variable experiment):
// out[m][j] = sum_k relu(HA[m][k] + HBT[k][j]) * W2[k] + b2
// 1024 blocks x 256 thr. Tile 16m x 64j, k in two 128-phases.
// Hot loop is DS-only: ha/w2 = wave-uniform ds_read_b128 broadcasts;
// hb = lane-indexed ds_read_b32 (2-way aliasing = free).
__global__ __launch_bounds__(256, 3) void pair_kernel(
    const float* __restrict__ HA, const float* __restrict__ HBT,
    const float* __restrict__ W2, const float* __restrict__ b2,
    float* __restrict__ out)
{
    __shared__ __align__(16) float lds[2048 + 8192 + 128];
    float* lha = lds;              // [m(16)][k(128)]
    float* lhb = lds + 2048;       // [k(128)][j(64)]
    float* lw2 = lds + 2048 + 8192;

    const int t = threadIdx.x;
    const int lane = t & 63;
    const int wave = t >> 6;
    const int jbase = (blockIdx.x & 15) * 64;       // 16 j-tiles
    const int mbase = (blockIdx.x >> 4) * 16;       // 64 m-tiles
    const int wm = wave * 4;                        // wave's m offset in tile

    f32x2 acc[4];
    #pragma unroll
    for (int mm = 0; mm < 4; ++mm) { acc[mm].x = 0.0f; acc[mm].y = 0.0f; }

    for (int kb = 0; kb < KK; kb += 128) {
        if (kb) __syncthreads();                    // WAR: done reading previous tile

        #pragma unroll
        for (int c = 0; c < 2; ++c) {               // HA tile: 2048 floats
            const int idx = c * 256 + t;
            const int row = idx >> 5, col = (idx & 31) << 2;
            *reinterpret_cast<float4*>(&lha[row * 128 + col]) =
                *reinterpret_cast<const float4*>(&HA[(mbase + row) * KK + kb + col]);
        }
        #pragma unroll
        for (int c = 0; c < 8; ++c) {               // HBT tile: 8192 floats
            const int idx = c * 256 + t;
            const int k = idx >> 4, col = (idx & 15) << 2;
            *reinterpret_cast<float4*>(&lhb[k * 64 + col]) =
                *reinterpret_cast<const float4*>(&HBT[(kb + k) * NN + jbase + col]);
        }
        if (t < 32)                                  // W2 chunk: 128 floats
            *reinterpret_cast<float4*>(&lw2[t * 4]) =
                *reinterpret_cast<const float4*>(&W2[kb + t * 4]);
        __syncthreads();

        #pragma unroll 4
        for (int k0 = 0; k0 < 128; k0 += 4) {
            f32x2 hb01, hb23;
            hb01.x = lhb[(k0 + 0) * 64 + lane];
            hb01.y = lhb[(k0 + 1) * 64 + lane];
            hb23.x = lhb[(k0 + 2) * 64 + lane];
            hb23.y = lhb[(k0 + 3) * 64 + lane];
            const float4 w4 = *reinterpret_cast<const float4*>(&lw2[k0]);
            f32x2 w01; w01.x = w4.x; w01.y = w4.y;
            f32x2 w23; w23.x = w4.z; w23.y = w4.w;
            #pragma unroll
            for (int mm = 0; mm < 4; ++mm) {
                const float4 a4 = *reinterpret_cast<const float4*>(&lha[(wm + mm) * 128 + k0]);
                f32x2 a01; a01.x = a4.x; a01.y = a4.y;
                f32x2 a23; a23.x = a4.z; a23.y = a4.w;
                f32x2 s;
                asm("v_pk_add_f32 %0, %1, %2" : "=v"(s) : "v"(a01), "v"(hb01));
                s.x = fmaxf(s.x, 0.0f);
                s.y = fmaxf(s.y, 0.0f);
                asm("v_pk_fma_f32 %0, %1, %2, %0" : "+v"(acc[mm]) : "v"(s), "v"(w01));
                f32x2 r;
                asm("v_pk_add_f32 %0, %1, %2" : "=v"(r) : "v"(a23), "v"(hb23));
                r.x = fmaxf(r.x, 0.0f);
                r.y = fmaxf(r.y, 0.0f);
                asm("v_pk_fma_f32 %0, %1, %2, %0" : "+v"(acc[mm]) : "v"(r), "v"(w23));
            }
        }
    }

    const float b2v = b2[0];
    #pragma unroll
    for (int mm = 0; mm < 4; ++mm)
        out[(mbase + wm + mm) * NN + jbase + lane] = acc[mm].x + acc[mm].y + b2v;
}

extern "C" void kernel_launch(void* const* d_in, const int* in_sizes, int n_in,
                              void* d_out, int out_size, void* d_ws, size_t ws_size,
                              hipStream_t stream) {
    const float* pred_a = (const float*)d_in[0];
    const float* pred_b = (const float*)d_in[1];
    const float* W1     = (const float*)d_in[2];
    const float* b1     = (const float*)d_in[3];
    const float* W2     = (const float*)d_in[4];
    const float* b2     = (const float*)d_in[5];
    float* out = (float*)d_out;

    float* HA  = (float*)d_ws;           // 1024*256 floats = 1 MB
    float* HBT = HA + NN * KK;           // 256*1024 floats = 1 MB

    prologue_kernel<<<512, 256, 0, stream>>>(pred_a, pred_b, W1, b1, HA, HBT);
    pair_kernel<<<1024, 256, 0, stream>>>(HA, HBT, W2, b2, out);
}

// Round 7
// 102.593 us; speedup vs baseline: 1.0591x; 1.0084x over previous
//
#include <hip/hip_runtime.h>

#define NN 1024   // pair count
#define HH 128    // hidden per side
#define KK 256    // 2*HIDDEN, premlp width

typedef float f32x2 __attribute__((ext_vector_type(2)));

// Prologue v2 (unchanged from round 6 — measured-neutral, keep):
//   HA [m][k] ([1024][256]) = dot(pred_a[m,:], W1[k,0:128]) + b1[k]
//   HBT[k][j] ([256][1024]) = dot(pred_b[j,:], W1[k,128:256])
__global__ __launch_bounds__(256, 2) void prologue_kernel(
    const float* __restrict__ pred_a, const float* __restrict__ pred_b,
    const float* __restrict__ W1, const float* __restrict__ b1,
    float* __restrict__ HA, float* __restrict__ HBT)
{
    __shared__ __align__(16) float lin[4 * HH];    // 4 input rows, 2 KB
    const int t = threadIdx.x;
    const int k = t;                               // output channel 0..255
    const bool isB = blockIdx.x & 1;
    const int rowbase = (blockIdx.x >> 1) * 4;     // 256 groups of 4 rows
    const float* __restrict__ src = isB ? pred_b : pred_a;
    const float* __restrict__ wrow = W1 + k * KK + (isB ? HH : 0);

    if (t < 128) {                                 // stage 4 input rows, coalesced
        const int row = t >> 5, col = (t & 31) << 2;
        *reinterpret_cast<float4*>(&lin[row * HH + col]) =
            *reinterpret_cast<const float4*>(&src[(rowbase + row) * HH + col]);
    }
    const float bias = isB ? 0.0f : b1[k];
    __syncthreads();

    float acc0 = 0.f, acc1 = 0.f, acc2 = 0.f, acc3 = 0.f;
    #pragma unroll 8
    for (int i0 = 0; i0 < HH; i0 += 4) {
        const float4 w = *reinterpret_cast<const float4*>(wrow + i0);  // per-lane VMEM
        const float4 p0 = *reinterpret_cast<const float4*>(&lin[0 * HH + i0]);  // broadcasts
        const float4 p1 = *reinterpret_cast<const float4*>(&lin[1 * HH + i0]);
        const float4 p2 = *reinterpret_cast<const float4*>(&lin[2 * HH + i0]);
        const float4 p3 = *reinterpret_cast<const float4*>(&lin[3 * HH + i0]);
        acc0 = fmaf(w.x,p0.x, fmaf(w.y,p0.y, fmaf(w.z,p0.z, fmaf(w.w,p0.w, acc0))));
        acc1 = fmaf(w.x,p1.x, fmaf(w.y,p1.y, fmaf(w.z,p1.z, fmaf(w.w,p1.w, acc1))));
        acc2 = fmaf(w.x,p2.x, fmaf(w.y,p2.y, fmaf(w.z,p2.z, fmaf(w.w,p2.w, acc2))));
        acc3 = fmaf(w.x,p3.x, fmaf(w.y,p3.y, fmaf(w.z,p3.z, fmaf(w.w,p3.w, acc3))));
    }

    if (!isB) {
        HA[(rowbase + 0) * KK + k] = acc0 + bias;  // coalesced over k
        HA[(rowbase + 1) * KK + k] = acc1 + bias;
        HA[(rowbase + 2) * KK + k] = acc2 + bias;
        HA[(rowbase + 3) * KK + k] = acc3 + bias;
    } else {
        float4 v = make_float4(acc0, acc1, acc2, acc3);
        *reinterpret_cast<float4*>(HBT + k * NN + rowbase) = v;  // 16B/lane
    }
}

// Pair kernel v3: out[m][j] = sum_k relu(HA[m][k] + HBT[k][j]) * W2[k] + b2
// 512 blocks x 256 thr. Tile 32m x 64j (was 16m): HBT re-reads halve, each
// hb/w2 broadcast amortizes over 8 m-rows. k in two 128-phases.
// LDS: lha[32][128] 16KB + lhb[128][64] 32KB + lw2[128] 0.5KB = 48.6KB -> 2/CU.
// Hot loop DS-only: ha/w2 wave-uniform b128 broadcasts (conflict-free),
// hb lane-indexed b32 (2-way aliasing = free).
__global__ __launch_bounds__(256, 2) void pair_kernel(
    const float* __restrict__ HA, const float* __restrict__ HBT,
    const float* __restrict__ W2, const float* __restrict__ b2,
    float* __restrict__ out)
{
    __shared__ __align__(16) float lds[4096 + 8192 + 128];
    float* lha = lds;              // [m(32)][k(128)]
    float* lhb = lds + 4096;       // [k(128)][j(64)]
    float* lw2 = lds + 4096 + 8192;

    const int t = threadIdx.x;
    const int lane = t & 63;
    const int wave = t >> 6;
    const int jbase = (blockIdx.x & 15) * 64;       // 16 j-tiles
    const int mbase = (blockIdx.x >> 4) * 32;       // 32 m-tiles
    const int wm = wave * 8;                        // wave's m offset in tile

    f32x2 acc[8];
    #pragma unroll
    for (int mm = 0; mm < 8; ++mm) { acc[mm].x = 0.0f; acc[mm].y = 0.0f; }

    for (int kb = 0; kb < KK; kb += 128) {
        if (kb) __syncthreads();                    // WAR: done reading previous tile

        #pragma unroll
        for (int c = 0; c < 4; ++c) {               // HA tile: 4096 floats
            const int idx = c * 256 + t;
            const int row = idx >> 5, col = (idx & 31) << 2;
            *reinterpret_cast<float4*>(&lha[row * 128 + col]) =
                *reinterpret_cast<const float4*>(&HA[(mbase + row) * KK + kb + col]);
        }
        #pragma unroll
        for (int c = 0; c < 8; ++c) {               // HBT tile: 8192 floats
            const int idx = c * 256 + t;
            const int k = idx >> 4, col = (idx & 15) << 2;
            *reinterpret_cast<float4*>(&lhb[k * 64 + col]) =
                *reinterpret_cast<const float4*>(&HBT[(kb + k) * NN + jbase + col]);
        }
        if (t < 32)                                  // W2 chunk: 128 floats
            *reinterpret_cast<float4*>(&lw2[t * 4]) =
                *reinterpret_cast<const float4*>(&W2[kb + t * 4]);
        __syncthreads();

        #pragma unroll 2
        for (int k0 = 0; k0 < 128; k0 += 4) {
            f32x2 hb01, hb23;
            hb01.x = lhb[(k0 + 0) * 64 + lane];      // ds_read_b32
            hb01.y = lhb[(k0 + 1) * 64 + lane];
            hb23.x = lhb[(k0 + 2) * 64 + lane];
            hb23.y = lhb[(k0 + 3) * 64 + lane];
            const float4 w4 = *reinterpret_cast<const float4*>(&lw2[k0]);  // broadcast
            f32x2 w01; w01.x = w4.x; w01.y = w4.y;
            f32x2 w23; w23.x = w4.z; w23.y = w4.w;
            #pragma unroll
            for (int mm = 0; mm < 8; ++mm) {
                const float4 a4 = *reinterpret_cast<const float4*>(&lha[(wm + mm) * 128 + k0]); // broadcast
                f32x2 a01; a01.x = a4.x; a01.y = a4.y;
                f32x2 a23; a23.x = a4.z; a23.y = a4.w;
                f32x2 s;
                asm("v_pk_add_f32 %0, %1, %2" : "=v"(s) : "v"(a01), "v"(hb01));
                s.x = fmaxf(s.x, 0.0f);
                s.y = fmaxf(s.y, 0.0f);
                asm("v_pk_fma_f32 %0, %1, %2, %0" : "+v"(acc[mm]) : "v"(s), "v"(w01));
                f32x2 r;
                asm("v_pk_add_f32 %0, %1, %2" : "=v"(r) : "v"(a23), "v"(hb23));
                r.x = fmaxf(r.x, 0.0f);
                r.y = fmaxf(r.y, 0.0f);
                asm("v_pk_fma_f32 %0, %1, %2, %0" : "+v"(acc[mm]) : "v"(r), "v"(w23));
            }
        }
    }

    const float b2v = b2[0];
    #pragma unroll
    for (int mm = 0; mm < 8; ++mm)
        out[(mbase + wm + mm) * NN + jbase + lane] = acc[mm].x + acc[mm].y + b2v;  // coalesced
}

extern "C" void kernel_launch(void* const* d_in, const int* in_sizes, int n_in,
                              void* d_out, int out_size, void* d_ws, size_t ws_size,
                              hipStream_t stream) {
    const float* pred_a = (const float*)d_in[0];
    const float* pred_b = (const float*)d_in[1];
    const float* W1     = (const float*)d_in[2];
    const float* b1     = (const float*)d_in[3];
    const float* W2     = (const float*)d_in[4];
    const float* b2     = (const float*)d_in[5];
    float* out = (float*)d_out;

    float* HA  = (float*)d_ws;           // 1024*256 floats = 1 MB
    float* HBT = HA + NN * KK;           // 256*1024 floats = 1 MB

    prologue_kernel<<<512, 256, 0, stream>>>(pred_a, pred_b, W1, b1, HA, HBT);
    pair_kernel<<<512, 256, 0, stream>>>(HA, HBT, W2, b2, out);
}